// Round 3
// baseline (179.044 us; speedup 1.0000x reference)
//
#include <hip/hip_runtime.h>
#include <math.h>

#define NUM_NODE 5000
#define BZ   64
#define SEQ  512
#define NBR  16
#define DIM  256
#define NCLS 20

#define ROWB    (DIM * 2)            // bf16 row bytes (512)
#define CW      8                    // waves (=positions) per gather block
#define NCHUNK  (SEQ / CW)           // 64 partial chunks per batch row
#define CVT_N4  (NUM_NODE * DIM / 4) // 320000 float4s
#define NCHUNK16 (SEQ / 16)          // fallback mapping

__device__ __forceinline__ int bcast_i(int v, int lane) {
    return __builtin_amdgcn_readlane(v, lane);   // uniform (SGPR) result
}
__device__ __forceinline__ float bcast_f(float v, int lane) {
    return __int_as_float(__builtin_amdgcn_readlane(__float_as_int(v), lane));
}
__device__ __forceinline__ unsigned bf16_rne(float f) {
    unsigned u = __float_as_uint(f);
    return (u + 0x7fffu + ((u >> 16) & 1u)) >> 16;
}
__device__ __forceinline__ float lo_bf16(unsigned u) { return __uint_as_float(u << 16); }
__device__ __forceinline__ float hi_bf16(unsigned u) { return __uint_as_float(u & 0xffff0000u); }

__global__ __launch_bounds__(256) void zero_ws_kernel(float* __restrict__ ws, int n) {
    int i = blockIdx.x * blockDim.x + threadIdx.x;
    if (i < n) ws[i] = 0.0f;
}

// fp32 (NUM_NODE,DIM) -> packed bf16 table (5 MB read, 2.56 MB write).
__global__ __launch_bounds__(256) void cvt_emb_kernel(
    const float4* __restrict__ src, uint2* __restrict__ dst, int n4) {
    int i = blockIdx.x * blockDim.x + threadIdx.x;
    if (i < n4) {
        float4 v = src[i];
        uint2 o;
        o.x = bf16_rne(v.x) | (bf16_rne(v.y) << 16);
        o.y = bf16_rne(v.z) | (bf16_rne(v.w) << 16);
        dst[i] = o;
    }
}

// Fused gather (round-0 structure, atomic-free epilogue). ONE position per
// wave. Issue order: EW -> edge_w chase first (the only HBM-cold long-latency
// chain), then NX-dependent row loads; vmcnt retires in issue order, so by
// the time the consume loop waits for the last row, the edge line has
// arrived — the ~900-cyc random miss hides entirely under the 9 row loads.
// 64-VGPR body at 8 waves/SIMD (proven 42 us fused in round 0). Epilogue:
// block LDS-combines its 8 positions and STREAMS the 1 KB chunk-sum to
// part[b][chunk][:] — zero atomics, zero init dependency; the head kernel
// folds the 64 chunks (4 MB streaming, ~1 us).
__global__ __launch_bounds__(512, 8) void gnn_gather_kernel(
    const int*   __restrict__ X,        // (BZ, SEQ)
    const int*   __restrict__ NX,       // (BZ, SEQ, NBR)
    const int*   __restrict__ EW,       // (BZ, SEQ, NBR)
    const char*  __restrict__ embb,     // (NUM_NODE, ROWB) packed bf16 table
    const float* __restrict__ edge_w,   // (EDGE_ROWS, 1)
    const float* __restrict__ node_w,   // (NUM_NODE, 1)
    float*       __restrict__ part)     // (BZ, NCHUNK, DIM) partials
{
    __shared__ float lds[CW][DIM];

    const int b     = blockIdx.x / NCHUNK;
    const int chunk = blockIdx.x % NCHUNK;
    const int wave  = threadIdx.x >> 6;
    const int lane  = threadIdx.x & 63;
    const int half  = lane >> 5;
    const int sub   = lane & 31;
    const int voff  = sub * 16;          // byte offset within a bf16 row

    const int s  = chunk * CW + wave;
    const int bs = b * SEQ + s;

    // EW first: start the one HBM-cold chase as early as possible.
    int   ewi = 0, nxv = 0;
    float ewv = 0.f;
    if (lane < NBR) {
        ewi = __builtin_nontemporal_load(&EW[bs * NBR + lane]);
        nxv = __builtin_nontemporal_load(&NX[bs * NBR + lane]);
    }
    if (lane < NBR)
        ewv = __builtin_nontemporal_load(&edge_w[ewi]);   // random, cold

    const int   x  = X[bs];        // wave-uniform address -> broadcast line
    const float nn = node_w[x];

    // ---- issue ALL row loads back-to-back (L2-resident bf16 table) ----
    uint4 e[8];
    #pragma unroll
    for (int j = 0; j < 8; ++j) {
        const int n0 = bcast_i(nxv, 2 * j);
        const int n1 = bcast_i(nxv, 2 * j + 1);
        const int n  = half ? n1 : n0;
        e[j] = *(const uint4*)(embb + (size_t)n * ROWB + voff);
    }
    const uint4 es = *(const uint4*)(embb + (size_t)x * ROWB + voff); // self row

    // ---- consume in issue order (decreasing vmcnt) ----
    float m[8];
    #pragma unroll
    for (int i = 0; i < 8; ++i) m[i] = -INFINITY;

    #pragma unroll
    for (int j = 0; j < 8; ++j) {
        const float w0 = bcast_f(ewv, 2 * j);
        const float w1 = bcast_f(ewv, 2 * j + 1);
        const float w  = half ? w1 : w0;
        m[0] = fmaxf(m[0], lo_bf16(e[j].x) * w);
        m[1] = fmaxf(m[1], hi_bf16(e[j].x) * w);
        m[2] = fmaxf(m[2], lo_bf16(e[j].y) * w);
        m[3] = fmaxf(m[3], hi_bf16(e[j].y) * w);
        m[4] = fmaxf(m[4], lo_bf16(e[j].z) * w);
        m[5] = fmaxf(m[5], hi_bf16(e[j].z) * w);
        m[6] = fmaxf(m[6], lo_bf16(e[j].w) * w);
        m[7] = fmaxf(m[7], hi_bf16(e[j].w) * w);
    }

    // combine the two half-wave neighbor subsets
    #pragma unroll
    for (int i = 0; i < 8; ++i)
        m[i] = fmaxf(m[i], __shfl_xor(m[i], 32));

    const float om = 1.0f - nn;
    float acc[8];
    acc[0] = om * m[0] + nn * lo_bf16(es.x);
    acc[1] = om * m[1] + nn * hi_bf16(es.x);
    acc[2] = om * m[2] + nn * lo_bf16(es.y);
    acc[3] = om * m[3] + nn * hi_bf16(es.y);
    acc[4] = om * m[4] + nn * lo_bf16(es.z);
    acc[5] = om * m[5] + nn * hi_bf16(es.z);
    acc[6] = om * m[6] + nn * lo_bf16(es.w);
    acc[7] = om * m[7] + nn * hi_bf16(es.w);

    if (half == 0) {
        *(float4*)&lds[wave][8 * sub]     = make_float4(acc[0], acc[1], acc[2], acc[3]);
        *(float4*)&lds[wave][8 * sub + 4] = make_float4(acc[4], acc[5], acc[6], acc[7]);
    }
    __syncthreads();

    if (threadIdx.x < DIM) {
        float ssum = 0.f;
        #pragma unroll
        for (int w2 = 0; w2 < CW; ++w2) ssum += lds[w2][threadIdx.x];
        part[((size_t)b * NCHUNK + chunk) * DIM + threadIdx.x] = ssum;  // streamed, no atomic
    }
}

// Fallback (tiny ws): fp32 gathers, atomic accumulation into (BZ,1,DIM).
__global__ __launch_bounds__(256) void gnn_gather_f32_kernel(
    const int*   __restrict__ X,
    const int*   __restrict__ NX,
    const int*   __restrict__ EW,
    const float* __restrict__ node_emb,
    const float* __restrict__ edge_w,
    const float* __restrict__ node_w,
    float*       __restrict__ dst)      // (BZ, DIM) atomic
{
    __shared__ float lds[4][DIM];
    const int b     = blockIdx.x / NCHUNK16;
    const int chunk = blockIdx.x % NCHUNK16;
    const int wave  = threadIdx.x >> 6;
    const int lane  = threadIdx.x & 63;
    const int s0  = chunk * 16 + wave * 4;
    const int bs0 = b * SEQ + s0;

    const int   nx  = NX[bs0 * NBR + lane];
    const float ew  = edge_w[EW[bs0 * NBR + lane]];
    int xv = 0; float nwv = 0.f;
    if (lane < 4) { xv = X[bs0 + lane]; nwv = node_w[xv]; }

    float4 acc = make_float4(0.f, 0.f, 0.f, 0.f);
    for (int p = 0; p < 4; ++p) {
        float4 m = make_float4(-INFINITY, -INFINITY, -INFINITY, -INFINITY);
        for (int k = 0; k < NBR; ++k) {
            const int   n = bcast_i(nx, p * 16 + k);
            const float w = bcast_f(ew, p * 16 + k);
            const float4 e = *(const float4*)(node_emb + (size_t)n * DIM + 4 * lane);
            m.x = fmaxf(m.x, e.x * w); m.y = fmaxf(m.y, e.y * w);
            m.z = fmaxf(m.z, e.z * w); m.w = fmaxf(m.w, e.w * w);
        }
        const int   x  = bcast_i(xv, p);
        const float nn = bcast_f(nwv, p);
        const float om = 1.0f - nn;
        const float4 r = *(const float4*)(node_emb + (size_t)x * DIM + 4 * lane);
        acc.x += om * m.x + nn * r.x; acc.y += om * m.y + nn * r.y;
        acc.z += om * m.z + nn * r.z; acc.w += om * m.w + nn * r.w;
    }
    *(float4*)&lds[wave][4 * lane] = acc;
    __syncthreads();
    const int t = threadIdx.x;
    atomicAdd(&dst[b * DIM + t], lds[0][t] + lds[1][t] + lds[2][t] + lds[3][t]);
}

// One block (256 threads) per batch row: fold nchunk partials (streaming)
// then GEMV(256->20) + bias + relu + log_softmax.
__global__ __launch_bounds__(256) void gnn_head_kernel(
    const float* __restrict__ part,  // (BZ, nchunk, DIM)
    const int                 nchunk,
    const float* __restrict__ fc_W,  // (NCLS, DIM)
    const float* __restrict__ fc_b,  // (NCLS,)
    float*       __restrict__ out)   // (BZ, NCLS)
{
    __shared__ float4 lds4[4][64];
    __shared__ float vals[NCLS];
    __shared__ float lse;

    const int b = blockIdx.x;
    const int t = threadIdx.x;
    const int wave = t >> 6;
    const int lane = t & 63;

    // fold partials: wave w sums chunks w, w+4, w+8, ...
    float4 y = make_float4(0.f, 0.f, 0.f, 0.f);
    for (int c = wave; c < nchunk; c += 4) {
        const float4 v = *(const float4*)(part + ((size_t)b * nchunk + c) * DIM + 4 * lane);
        y.x += v.x; y.y += v.y; y.z += v.z; y.w += v.w;
    }
    lds4[wave][lane] = y;
    __syncthreads();
    const float4 a0 = lds4[0][lane], a1 = lds4[1][lane];
    const float4 a2 = lds4[2][lane], a3 = lds4[3][lane];
    const float4 y4 = make_float4(a0.x + a1.x + a2.x + a3.x,
                                  a0.y + a1.y + a2.y + a3.y,
                                  a0.z + a1.z + a2.z + a3.z,
                                  a0.w + a1.w + a2.w + a3.w);

    #pragma unroll
    for (int ci = 0; ci < 5; ++ci) {
        const int c = wave * 5 + ci;           // 4 waves x 5 classes = 20
        const float4 w4 = *(const float4*)(fc_W + c * DIM + 4 * lane);
        float d = y4.x * w4.x + y4.y * w4.y + y4.z * w4.z + y4.w * w4.w;
        #pragma unroll
        for (int off = 32; off; off >>= 1) d += __shfl_xor(d, off);
        if (lane == 0) vals[c] = fmaxf(d + fc_b[c], 0.0f);
    }
    __syncthreads();

    if (t == 0) {
        float mx = -INFINITY;
        for (int c = 0; c < NCLS; ++c) mx = fmaxf(mx, vals[c]);
        float s = 0.0f;
        for (int c = 0; c < NCLS; ++c) s += expf(vals[c] - mx);
        lse = mx + logf(s);
    }
    __syncthreads();

    if (t < NCLS) out[b * NCLS + t] = vals[t] - lse;
}

extern "C" void kernel_launch(void* const* d_in, const int* in_sizes, int n_in,
                              void* d_out, int out_size, void* d_ws, size_t ws_size,
                              hipStream_t stream) {
    const int*   X        = (const int*)  d_in[0];
    const int*   NX       = (const int*)  d_in[1];
    const int*   EW       = (const int*)  d_in[2];
    const float* node_emb = (const float*)d_in[3];
    const float* edge_w   = (const float*)d_in[4];
    const float* node_w   = (const float*)d_in[5];
    const float* fc_W     = (const float*)d_in[6];
    const float* fc_b     = (const float*)d_in[7];
    float* out = (float*)d_out;

    const size_t part_bytes = (size_t)BZ * NCHUNK * DIM * sizeof(float);        // 4 MB
    const size_t emb_bytes  = (size_t)NUM_NODE * DIM * sizeof(unsigned short);  // 2.56 MB
    float* part = (float*)d_ws;
    char*  embb = (char*)d_ws + part_bytes;

    if (ws_size >= part_bytes + emb_bytes) {
        cvt_emb_kernel<<<(CVT_N4 + 255) / 256, 256, 0, stream>>>(
            (const float4*)node_emb, (uint2*)embb, CVT_N4);
        gnn_gather_kernel<<<BZ * NCHUNK, 512, 0, stream>>>(
            X, NX, EW, embb, edge_w, node_w, part);
        gnn_head_kernel<<<BZ, 256, 0, stream>>>(part, NCHUNK, fc_W, fc_b, out);
    } else {
        zero_ws_kernel<<<(BZ * DIM + 255) / 256, 256, 0, stream>>>(part, BZ * DIM);
        gnn_gather_f32_kernel<<<BZ * NCHUNK16, 256, 0, stream>>>(
            X, NX, EW, node_emb, edge_w, node_w, part);
        gnn_head_kernel<<<BZ, 256, 0, stream>>>(part, 1, fc_W, fc_b, out);
    }
}

// Round 4
// 176.090 us; speedup vs baseline: 1.0168x; 1.0168x over previous
//
#include <hip/hip_runtime.h>
#include <math.h>

#define NUM_NODE 5000
#define BZ   64
#define SEQ  512
#define NBR  16
#define DIM  256
#define NCLS 20

#define ROWB8   DIM                  // fp8 row bytes (256)
#define ESCALE  256.0f               // table scale (values ~0.02 -> ~5, e4m3 sweet spot)
#define CW      8                    // waves (=positions) per gather block
#define NCHUNK  (SEQ / CW)           // 64 partial chunks per batch row
#define CVT_N4  (NUM_NODE * DIM / 4) // 320000 float4s
#define NCHUNK16 (SEQ / 16)          // fallback mapping

typedef float v2f __attribute__((ext_vector_type(2)));

__device__ __forceinline__ int bcast_i(int v, int lane) {
    return __builtin_amdgcn_readlane(v, lane);   // uniform (SGPR) result
}
__device__ __forceinline__ float bcast_f(float v, int lane) {
    return __int_as_float(__builtin_amdgcn_readlane(__float_as_int(v), lane));
}

__global__ __launch_bounds__(256) void zero_ws_kernel(float* __restrict__ ws, int n) {
    int i = blockIdx.x * blockDim.x + threadIdx.x;
    if (i < n) ws[i] = 0.0f;
}

// fp32 (NUM_NODE,DIM) -> scaled fp8 e4m3 table (5 MB read, 1.28 MB write).
// Scale x256 puts |values| (~0.02..0.1) at 5..26 — mid-range e4m3 normals.
__global__ __launch_bounds__(256) void cvt_emb_kernel(
    const float4* __restrict__ src, unsigned* __restrict__ dst, int n4) {
    int i = blockIdx.x * blockDim.x + threadIdx.x;
    if (i < n4) {
        float4 v = src[i];
        int r = 0;
        r = __builtin_amdgcn_cvt_pk_fp8_f32(v.x * ESCALE, v.y * ESCALE, r, false);
        r = __builtin_amdgcn_cvt_pk_fp8_f32(v.z * ESCALE, v.w * ESCALE, r, true);
        dst[i] = (unsigned)r;
    }
}

// Fused gather, fp8 rows. ONE position per wave; a uint2 (8B)/lane load
// covers TWO 256B fp8 rows (lanes 0-31 -> neighbor 2j, 32-63 -> 2j+1):
// neighborhood = 8 loads + self, at 8 cache lines per load instead of
// bf16's 16. Per-position line-requests drop ~146 -> ~74 L2 lines
// (+16 HBM-cold edge lines) — per-CU miss-slot model predicts ~30 us
// (vs ~42 measured for bf16). Consume order = issue order (vmcnt retires
// in-order) so the early EW->edge_w chase completes under the row loads.
// Epilogue: block LDS-combines its 8 positions, un-scales by 1/ESCALE,
// streams the 1 KB chunk-sum to part[b][chunk][:] — no atomics, no init.
__global__ __launch_bounds__(512, 8) void gnn_gather_kernel(
    const int*   __restrict__ X,        // (BZ, SEQ)
    const int*   __restrict__ NX,       // (BZ, SEQ, NBR)
    const int*   __restrict__ EW,       // (BZ, SEQ, NBR)
    const char*  __restrict__ emb8,     // (NUM_NODE, ROWB8) scaled fp8 table
    const float* __restrict__ edge_w,   // (EDGE_ROWS, 1)
    const float* __restrict__ node_w,   // (NUM_NODE, 1)
    float*       __restrict__ part)     // (BZ, NCHUNK, DIM) partials
{
    __shared__ float lds[CW][DIM];

    const int b     = blockIdx.x / NCHUNK;
    const int chunk = blockIdx.x % NCHUNK;
    const int wave  = threadIdx.x >> 6;
    const int lane  = threadIdx.x & 63;
    const int half  = lane >> 5;
    const int sub   = lane & 31;
    const int voff  = sub * 8;           // byte offset within an fp8 row

    const int s  = chunk * CW + wave;
    const int bs = b * SEQ + s;

    // EW first: start the one HBM-cold chase as early as possible.
    int   ewi = 0, nxv = 0;
    float ewv = 0.f;
    if (lane < NBR) {
        ewi = __builtin_nontemporal_load(&EW[bs * NBR + lane]);
        nxv = __builtin_nontemporal_load(&NX[bs * NBR + lane]);
    }
    if (lane < NBR)
        ewv = __builtin_nontemporal_load(&edge_w[ewi]);   // random, cold

    const int   x  = X[bs];        // wave-uniform address -> broadcast line
    const float nn = node_w[x];

    // ---- issue ALL row loads back-to-back (L2-resident fp8 table) ----
    uint2 e[8];
    #pragma unroll
    for (int j = 0; j < 8; ++j) {
        const int n0 = bcast_i(nxv, 2 * j);
        const int n1 = bcast_i(nxv, 2 * j + 1);
        const int n  = half ? n1 : n0;
        e[j] = *(const uint2*)(emb8 + (size_t)n * ROWB8 + voff);
    }
    const uint2 es = *(const uint2*)(emb8 + (size_t)x * ROWB8 + voff); // self row

    // ---- consume in issue order (decreasing vmcnt) ----
    float m[8];
    #pragma unroll
    for (int i = 0; i < 8; ++i) m[i] = -INFINITY;

    #pragma unroll
    for (int j = 0; j < 8; ++j) {
        const float w0 = bcast_f(ewv, 2 * j);
        const float w1 = bcast_f(ewv, 2 * j + 1);
        const float w  = half ? w1 : w0;
        const v2f a0 = __builtin_amdgcn_cvt_pk_f32_fp8((int)e[j].x, false);
        const v2f a1 = __builtin_amdgcn_cvt_pk_f32_fp8((int)e[j].x, true);
        const v2f a2 = __builtin_amdgcn_cvt_pk_f32_fp8((int)e[j].y, false);
        const v2f a3 = __builtin_amdgcn_cvt_pk_f32_fp8((int)e[j].y, true);
        m[0] = fmaxf(m[0], a0.x * w);
        m[1] = fmaxf(m[1], a0.y * w);
        m[2] = fmaxf(m[2], a1.x * w);
        m[3] = fmaxf(m[3], a1.y * w);
        m[4] = fmaxf(m[4], a2.x * w);
        m[5] = fmaxf(m[5], a2.y * w);
        m[6] = fmaxf(m[6], a3.x * w);
        m[7] = fmaxf(m[7], a3.y * w);
    }

    // combine the two half-wave neighbor subsets
    #pragma unroll
    for (int i = 0; i < 8; ++i)
        m[i] = fmaxf(m[i], __shfl_xor(m[i], 32));

    const v2f s0 = __builtin_amdgcn_cvt_pk_f32_fp8((int)es.x, false);
    const v2f s1 = __builtin_amdgcn_cvt_pk_f32_fp8((int)es.x, true);
    const v2f s2 = __builtin_amdgcn_cvt_pk_f32_fp8((int)es.y, false);
    const v2f s3 = __builtin_amdgcn_cvt_pk_f32_fp8((int)es.y, true);

    const float om = 1.0f - nn;
    float acc[8];
    acc[0] = om * m[0] + nn * s0.x;
    acc[1] = om * m[1] + nn * s0.y;
    acc[2] = om * m[2] + nn * s1.x;
    acc[3] = om * m[3] + nn * s1.y;
    acc[4] = om * m[4] + nn * s2.x;
    acc[5] = om * m[5] + nn * s2.y;
    acc[6] = om * m[6] + nn * s3.x;
    acc[7] = om * m[7] + nn * s3.y;

    if (half == 0) {
        *(float4*)&lds[wave][8 * sub]     = make_float4(acc[0], acc[1], acc[2], acc[3]);
        *(float4*)&lds[wave][8 * sub + 4] = make_float4(acc[4], acc[5], acc[6], acc[7]);
    }
    __syncthreads();

    if (threadIdx.x < DIM) {
        float ssum = 0.f;
        #pragma unroll
        for (int w2 = 0; w2 < CW; ++w2) ssum += lds[w2][threadIdx.x];
        // un-scale the x256 table here (one multiply per output element)
        part[((size_t)b * NCHUNK + chunk) * DIM + threadIdx.x] = ssum * (1.0f / ESCALE);
    }
}

// Fallback (tiny ws): fp32 gathers, atomic accumulation into (BZ,DIM).
__global__ __launch_bounds__(256) void gnn_gather_f32_kernel(
    const int*   __restrict__ X,
    const int*   __restrict__ NX,
    const int*   __restrict__ EW,
    const float* __restrict__ node_emb,
    const float* __restrict__ edge_w,
    const float* __restrict__ node_w,
    float*       __restrict__ dst)      // (BZ, DIM) atomic
{
    __shared__ float lds[4][DIM];
    const int b     = blockIdx.x / NCHUNK16;
    const int chunk = blockIdx.x % NCHUNK16;
    const int wave  = threadIdx.x >> 6;
    const int lane  = threadIdx.x & 63;
    const int s0  = chunk * 16 + wave * 4;
    const int bs0 = b * SEQ + s0;

    const int   nx  = NX[bs0 * NBR + lane];
    const float ew  = edge_w[EW[bs0 * NBR + lane]];
    int xv = 0; float nwv = 0.f;
    if (lane < 4) { xv = X[bs0 + lane]; nwv = node_w[xv]; }

    float4 acc = make_float4(0.f, 0.f, 0.f, 0.f);
    for (int p = 0; p < 4; ++p) {
        float4 m = make_float4(-INFINITY, -INFINITY, -INFINITY, -INFINITY);
        for (int k = 0; k < NBR; ++k) {
            const int   n = bcast_i(nx, p * 16 + k);
            const float w = bcast_f(ew, p * 16 + k);
            const float4 e = *(const float4*)(node_emb + (size_t)n * DIM + 4 * lane);
            m.x = fmaxf(m.x, e.x * w); m.y = fmaxf(m.y, e.y * w);
            m.z = fmaxf(m.z, e.z * w); m.w = fmaxf(m.w, e.w * w);
        }
        const int   x  = bcast_i(xv, p);
        const float nn = bcast_f(nwv, p);
        const float om = 1.0f - nn;
        const float4 r = *(const float4*)(node_emb + (size_t)x * DIM + 4 * lane);
        acc.x += om * m.x + nn * r.x; acc.y += om * m.y + nn * r.y;
        acc.z += om * m.z + nn * r.z; acc.w += om * m.w + nn * r.w;
    }
    *(float4*)&lds[wave][4 * lane] = acc;
    __syncthreads();
    const int t = threadIdx.x;
    atomicAdd(&dst[b * DIM + t], lds[0][t] + lds[1][t] + lds[2][t] + lds[3][t]);
}

// One block (256 threads) per batch row: fold nchunk partials (streaming)
// then GEMV(256->20) + bias + relu + log_softmax.
__global__ __launch_bounds__(256) void gnn_head_kernel(
    const float* __restrict__ part,  // (BZ, nchunk, DIM)
    const int                 nchunk,
    const float* __restrict__ fc_W,  // (NCLS, DIM)
    const float* __restrict__ fc_b,  // (NCLS,)
    float*       __restrict__ out)   // (BZ, NCLS)
{
    __shared__ float4 lds4[4][64];
    __shared__ float vals[NCLS];
    __shared__ float lse;

    const int b = blockIdx.x;
    const int t = threadIdx.x;
    const int wave = t >> 6;
    const int lane = t & 63;

    // fold partials: wave w sums chunks w, w+4, w+8, ...
    float4 y = make_float4(0.f, 0.f, 0.f, 0.f);
    for (int c = wave; c < nchunk; c += 4) {
        const float4 v = *(const float4*)(part + ((size_t)b * nchunk + c) * DIM + 4 * lane);
        y.x += v.x; y.y += v.y; y.z += v.z; y.w += v.w;
    }
    lds4[wave][lane] = y;
    __syncthreads();
    const float4 a0 = lds4[0][lane], a1 = lds4[1][lane];
    const float4 a2 = lds4[2][lane], a3 = lds4[3][lane];
    const float4 y4 = make_float4(a0.x + a1.x + a2.x + a3.x,
                                  a0.y + a1.y + a2.y + a3.y,
                                  a0.z + a1.z + a2.z + a3.z,
                                  a0.w + a1.w + a2.w + a3.w);

    #pragma unroll
    for (int ci = 0; ci < 5; ++ci) {
        const int c = wave * 5 + ci;           // 4 waves x 5 classes = 20
        const float4 w4 = *(const float4*)(fc_W + c * DIM + 4 * lane);
        float d = y4.x * w4.x + y4.y * w4.y + y4.z * w4.z + y4.w * w4.w;
        #pragma unroll
        for (int off = 32; off; off >>= 1) d += __shfl_xor(d, off);
        if (lane == 0) vals[c] = fmaxf(d + fc_b[c], 0.0f);
    }
    __syncthreads();

    if (t == 0) {
        float mx = -INFINITY;
        for (int c = 0; c < NCLS; ++c) mx = fmaxf(mx, vals[c]);
        float s = 0.0f;
        for (int c = 0; c < NCLS; ++c) s += expf(vals[c] - mx);
        lse = mx + logf(s);
    }
    __syncthreads();

    if (t < NCLS) out[b * NCLS + t] = vals[t] - lse;
}

extern "C" void kernel_launch(void* const* d_in, const int* in_sizes, int n_in,
                              void* d_out, int out_size, void* d_ws, size_t ws_size,
                              hipStream_t stream) {
    const int*   X        = (const int*)  d_in[0];
    const int*   NX       = (const int*)  d_in[1];
    const int*   EW       = (const int*)  d_in[2];
    const float* node_emb = (const float*)d_in[3];
    const float* edge_w   = (const float*)d_in[4];
    const float* node_w   = (const float*)d_in[5];
    const float* fc_W     = (const float*)d_in[6];
    const float* fc_b     = (const float*)d_in[7];
    float* out = (float*)d_out;

    const size_t part_bytes = (size_t)BZ * NCHUNK * DIM * sizeof(float);  // 4 MB
    const size_t emb_bytes  = (size_t)NUM_NODE * DIM;                     // 1.28 MB fp8
    float* part = (float*)d_ws;
    char*  emb8 = (char*)d_ws + part_bytes;

    if (ws_size >= part_bytes + emb_bytes) {
        cvt_emb_kernel<<<(CVT_N4 + 255) / 256, 256, 0, stream>>>(
            (const float4*)node_emb, (unsigned*)emb8, CVT_N4);
        gnn_gather_kernel<<<BZ * NCHUNK, 512, 0, stream>>>(
            X, NX, EW, emb8, edge_w, node_w, part);
        gnn_head_kernel<<<BZ, 256, 0, stream>>>(part, NCHUNK, fc_W, fc_b, out);
    } else {
        zero_ws_kernel<<<(BZ * DIM + 255) / 256, 256, 0, stream>>>(part, BZ * DIM);
        gnn_gather_f32_kernel<<<BZ * NCHUNK16, 256, 0, stream>>>(
            X, NX, EW, node_emb, edge_w, node_w, part);
        gnn_head_kernel<<<BZ, 256, 0, stream>>>(part, 1, fc_W, fc_b, out);
    }
}